// Round 8
// baseline (718.493 us; speedup 1.0000x reference)
//
#include <hip/hip_runtime.h>
#include <cstddef>
#include <math.h>

#define T_TOK 2048
#define F_DIM 512
#define H_DIM 1024
#define V_DIM 32000
#define VHALF 16000
#define NKC   25
#define KC    640
#define LN_EPS 1e-5f
#define SHIFT 20.0f

typedef __attribute__((ext_vector_type(8))) short bf16x8;
typedef __attribute__((ext_vector_type(4))) float f32x4;

__device__ __forceinline__ unsigned short f2bf(float x) {
  unsigned int u = __float_as_uint(x);
  u += 0x7fffu + ((u >> 16) & 1u);
  return (unsigned short)(u >> 16);
}

// async global->LDS, 16B per lane; LDS dest = wave-uniform base + lane*16
__device__ __forceinline__ void gld16(const unsigned short* gsrc, unsigned short* ldst) {
  __builtin_amdgcn_global_load_lds(
      (const __attribute__((address_space(1))) unsigned int*)gsrc,
      (__attribute__((address_space(3))) unsigned int*)ldst, 16, 0, 0);
}

__device__ inline float wave_sum(float x) {
#pragma unroll
  for (int off = 32; off > 0; off >>= 1) x += __shfl_xor(x, off, 64);
  return x;
}

// ---------------- zero ----------------
__global__ void zero_kernel(float* __restrict__ p, int n) {
  int i = blockIdx.x * 256 + threadIdx.x;
  if (i < n) p[i] = 0.f;
}

__global__ void zero4_kernel(float4* __restrict__ p, int n4) {
  int i = blockIdx.x * 256 + threadIdx.x;
  if (i < n4) {
    float4 z; z.x = 0.f; z.y = 0.f; z.z = 0.f; z.w = 0.f;
    p[i] = z;
  }
}

// fused zeroing of up to 4 small arrays (one launch instead of four)
__global__ void zero_multi_kernel(float* __restrict__ a, int na,
                                  float* __restrict__ b, int nb,
                                  float* __restrict__ c, int nc,
                                  float* __restrict__ d, int nd) {
  int i = blockIdx.x * 256 + threadIdx.x;
  if (i < na) a[i] = 0.f;
  if (i < nb) b[i] = 0.f;
  if (i < nc) c[i] = 0.f;
  if (i < nd) d[i] = 0.f;
}

// -- sum nslab slabs of n4 float4s; opt. bias (row width F_DIM), relu, mask ---
// mask semantics match gemm_bf_nt epilogue: component zeroed where !(mask>0).
__global__ __launch_bounds__(256) void reduceK_kernel(
    const float4* __restrict__ parts, float4* __restrict__ out, int n4, int nslab,
    const float* __restrict__ bias1, const float* __restrict__ bias2, int relu,
    const float* __restrict__ maskv) {
  const int i = blockIdx.x * 256 + threadIdx.x;
  if (i >= n4) return;
  float4 s = parts[i];
  for (int k = 1; k < nslab; ++k) {
    float4 p = parts[(size_t)k * n4 + i];
    s.x += p.x; s.y += p.y; s.z += p.z; s.w += p.w;
  }
  const int c = (i & (F_DIM / 4 - 1)) * 4;
  if (bias1) {
    float4 b = *(const float4*)(bias1 + c);
    s.x += b.x; s.y += b.y; s.z += b.z; s.w += b.w;
  }
  if (bias2) {
    float4 b = *(const float4*)(bias2 + c);
    s.x += b.x; s.y += b.y; s.z += b.z; s.w += b.w;
  }
  if (relu) {
    s.x = fmaxf(s.x, 0.f); s.y = fmaxf(s.y, 0.f);
    s.z = fmaxf(s.z, 0.f); s.w = fmaxf(s.w, 0.f);
  }
  if (maskv) {
    float4 m = ((const float4*)maskv)[i];
    if (!(m.x > 0.f)) s.x = 0.f;
    if (!(m.y > 0.f)) s.y = 0.f;
    if (!(m.z > 0.f)) s.z = 0.f;
    if (!(m.w > 0.f)) s.w = 0.f;
  }
  out[i] = s;
}

// ---------------- fp32 [R,C] -> bf16 [C,R] (transpose) ------------------------
__global__ __launch_bounds__(256) void convT_kernel(
    const float* __restrict__ in, unsigned short* __restrict__ out, int R, int C) {
  __shared__ unsigned short tile[64][65];
  const int r0 = blockIdx.x * 64, c0 = blockIdx.y * 64;
  const int rr = threadIdx.x >> 4, cc4 = (threadIdx.x & 15) * 4;
#pragma unroll
  for (int ps = 0; ps < 4; ++ps) {
    const int row = ps * 16 + rr;
    float4 x = *(const float4*)&in[(size_t)(r0 + row) * C + c0 + cc4];
    tile[row][cc4 + 0] = f2bf(x.x); tile[row][cc4 + 1] = f2bf(x.y);
    tile[row][cc4 + 2] = f2bf(x.z); tile[row][cc4 + 3] = f2bf(x.w);
  }
  __syncthreads();
#pragma unroll
  for (int ps = 0; ps < 4; ++ps) {
    const int orow = ps * 16 + rr;
    ushort4 u;
    u.x = tile[cc4 + 0][orow]; u.y = tile[cc4 + 1][orow];
    u.z = tile[cc4 + 2][orow]; u.w = tile[cc4 + 3][orow];
    *(ushort4*)&out[(size_t)(c0 + orow) * R + r0 + cc4] = u;
  }
}

// ---------------- convert E to bf16 (row-major) + bf16 transposed ------------
__global__ __launch_bounds__(256) void convertE_kernel(
    const float* __restrict__ E, unsigned short* __restrict__ Ebf,
    unsigned short* __restrict__ Etbf)
{
  __shared__ float tile[64][65];
  const int tid = threadIdx.x;
  const int v0 = blockIdx.x * 64, f0 = blockIdx.y * 64;
  const int r = tid >> 4, cq = (tid & 15) * 4;
#pragma unroll
  for (int ps = 0; ps < 4; ++ps) {
    const int row = ps * 16 + r;
    float4 x = *(const float4*)&E[(size_t)(v0 + row) * F_DIM + f0 + cq];
    tile[row][cq + 0] = x.x; tile[row][cq + 1] = x.y;
    tile[row][cq + 2] = x.z; tile[row][cq + 3] = x.w;
    ushort4 u; u.x = f2bf(x.x); u.y = f2bf(x.y); u.z = f2bf(x.z); u.w = f2bf(x.w);
    *(ushort4*)&Ebf[(size_t)(v0 + row) * F_DIM + f0 + cq] = u;
  }
  __syncthreads();
#pragma unroll
  for (int ps = 0; ps < 4; ++ps) {
    const int frow = ps * 16 + r;
    ushort4 u;
    u.x = f2bf(tile[cq + 0][frow]); u.y = f2bf(tile[cq + 1][frow]);
    u.z = f2bf(tile[cq + 2][frow]); u.w = f2bf(tile[cq + 3][frow]);
    *(ushort4*)&Etbf[(size_t)(f0 + frow) * V_DIM + v0 + cq] = u;
  }
}

// ---------------- generic bf16 NT GEMM: C[M,N] = A[M,K] * B[N,K]^T ------------
// Used only OUTSIDE the c_t precision chain (dv, gWh).
// gridDim.z>1: atomic_f=1 -> atomicAdd; atomic_f=0 -> slab mode (plain stores
// at outf + z*M*N; reduceK sums slabs).
__global__ __launch_bounds__(256, 2) void gemm_bf_nt_kernel(
    const unsigned short* __restrict__ A, const unsigned short* __restrict__ B,
    int M, int N, int K,
    const float* __restrict__ maskv,
    float* __restrict__ outf, int atomic_f)
{
  __shared__ __align__(16) unsigned short As[128 * 64];
  __shared__ __align__(16) unsigned short Bs[128 * 64];
  const int tid = threadIdx.x;
  const int w = tid >> 6, lane = tid & 63;
  const int c15 = lane & 15, q = lane >> 4;
  const int n0 = blockIdx.x * 128, m0 = blockIdx.y * 128;
  const int kc = K / gridDim.z;
  const int kbase = blockIdx.z * kc;
  const int mw = (w & 1) * 64, nw = (w >> 1) * 64;
  float* __restrict__ outp = outf;
  if (!atomic_f && gridDim.z > 1) outp = outf + (size_t)blockIdx.z * M * N;
  f32x4 acc[4][4];
#pragma unroll
  for (int mi = 0; mi < 4; ++mi)
#pragma unroll
    for (int nj = 0; nj < 4; ++nj) acc[mi][nj] = (f32x4){0.f, 0.f, 0.f, 0.f};
  for (int it = 0; it < kc / 64; ++it) {
    const int kb = kbase + it * 64;
#pragma unroll
    for (int i = 0; i < 4; ++i) {
      const int gid = (w * 4 + i) * 64 + lane;
      const int row = gid >> 3, col = gid & 7;
      const int colsrc = col ^ (row & 7);
      gld16(A + (size_t)(m0 + row) * K + kb + colsrc * 8, &As[(w * 4 + i) * 512]);
      gld16(B + (size_t)(n0 + row) * K + kb + colsrc * 8, &Bs[(w * 4 + i) * 512]);
    }
    __syncthreads();
#pragma unroll
    for (int kk = 0; kk < 2; ++kk) {
      const int g = (kk * 4 + q) ^ (c15 & 7);
      bf16x8 af[4], bfr[4];
#pragma unroll
      for (int mi = 0; mi < 4; ++mi) {
        const int row = mw + mi * 16 + c15;
        af[mi] = *(const bf16x8*)&As[(row * 8 + g) * 8];
      }
#pragma unroll
      for (int nj = 0; nj < 4; ++nj) {
        const int row = nw + nj * 16 + c15;
        bfr[nj] = *(const bf16x8*)&Bs[(row * 8 + g) * 8];
      }
#pragma unroll
      for (int mi = 0; mi < 4; ++mi)
#pragma unroll
        for (int nj = 0; nj < 4; ++nj)
          acc[mi][nj] = __builtin_amdgcn_mfma_f32_16x16x32_bf16(af[mi], bfr[nj], acc[mi][nj], 0, 0, 0);
    }
    __syncthreads();
  }
#pragma unroll
  for (int mi = 0; mi < 4; ++mi)
#pragma unroll
    for (int nj = 0; nj < 4; ++nj) {
      const int n = n0 + nw + nj * 16 + c15;
#pragma unroll
      for (int r = 0; r < 4; ++r) {
        const int m = m0 + mw + mi * 16 + q * 4 + r;
        const size_t idx = (size_t)m * N + n;
        float v = acc[mi][nj][r];
        if (maskv && !(maskv[idx] > 0.f)) v = 0.f;
        if (atomic_f) atomicAdd(outf + idx, v); else outp[idx] = v;
      }
    }
}

// ---------------- fp32 GEMM NT: C[M,N] = (A ⊙ A2)[M,K] * B[N,K]^T -------------
// Precision-critical chain (v, p, tmat). gridDim.z>1: deterministic slab
// split-K — each z writes a full partial at C + z*M*N (plain stores);
// reduceK_kernel (or fused consumer) sums slabs and applies bias/relu.
__global__ __launch_bounds__(256) void gemm_nt_kernel(
    const float* __restrict__ A, const float* __restrict__ A2,
    const float* __restrict__ B, float* __restrict__ C,
    int M, int N, int K,
    const float* __restrict__ bias1, const float* __restrict__ bias2, int relu)
{
  __shared__ float As[16][68];
  __shared__ float Bs[16][68];
  const int tid = threadIdx.x;
  const int m0 = blockIdx.y * 64, n0 = blockIdx.x * 64;
  const int ty = tid >> 4, tx = tid & 15;
  const int lrow = tid >> 2, lkq = (tid & 3) * 4;
  const int zc = gridDim.z;
  const int kc = K / zc;
  const int kbase = blockIdx.z * kc;
  float* __restrict__ Co = C + (size_t)blockIdx.z * M * N;
  float acc[4][4] = {};
  for (int k0 = kbase; k0 < kbase + kc; k0 += 16) {
    float4 a4 = *(const float4*)(A + (size_t)(m0 + lrow) * K + k0 + lkq);
    if (A2) {
      float4 u4 = *(const float4*)(A2 + (size_t)(m0 + lrow) * K + k0 + lkq);
      a4.x *= u4.x; a4.y *= u4.y; a4.z *= u4.z; a4.w *= u4.w;
    }
    float4 b4 = *(const float4*)(B + (size_t)(n0 + lrow) * K + k0 + lkq);
    As[lkq+0][lrow] = a4.x; As[lkq+1][lrow] = a4.y; As[lkq+2][lrow] = a4.z; As[lkq+3][lrow] = a4.w;
    Bs[lkq+0][lrow] = b4.x; Bs[lkq+1][lrow] = b4.y; Bs[lkq+2][lrow] = b4.z; Bs[lkq+3][lrow] = b4.w;
    __syncthreads();
#pragma unroll
    for (int k = 0; k < 16; ++k) {
      float4 a = *(const float4*)&As[k][ty*4];
      float4 b = *(const float4*)&Bs[k][tx*4];
      float ar[4] = {a.x,a.y,a.z,a.w}, br[4] = {b.x,b.y,b.z,b.w};
#pragma unroll
      for (int i = 0; i < 4; ++i)
#pragma unroll
        for (int j = 0; j < 4; ++j) acc[i][j] = fmaf(ar[i], br[j], acc[i][j]);
    }
    __syncthreads();
  }
  if (zc == 1) {
#pragma unroll
    for (int i = 0; i < 4; ++i) {
      const int m = m0 + ty*4 + i;
      float cr[4];
#pragma unroll
      for (int j = 0; j < 4; ++j) {
        const int n = n0 + tx*4 + j;
        float v = acc[i][j];
        if (bias1) v += bias1[n];
        if (bias2) v += bias2[n];
        if (relu) v = fmaxf(v, 0.f);
        cr[j] = v;
      }
      float4 c; c.x = cr[0]; c.y = cr[1]; c.z = cr[2]; c.w = cr[3];
      *(float4*)(C + (size_t)m * N + n0 + tx*4) = c;
    }
  } else {
#pragma unroll
    for (int i = 0; i < 4; ++i) {
      const int m = m0 + ty*4 + i;
      float4 c; c.x = acc[i][0]; c.y = acc[i][1]; c.z = acc[i][2]; c.w = acc[i][3];
      *(float4*)(Co + (size_t)m * N + n0 + tx*4) = c;
    }
  }
}

// ---------------- fp32 GEMM NN: C[M,N] = A[M,K] * B[K,N] ----------------------
// Precision-critical (u = v @ gWp). gridDim.z>1: slab split-K (see gemm_nt).
__global__ __launch_bounds__(256) void gemm_nn_kernel(
    const float* __restrict__ A, const float* __restrict__ B,
    float* __restrict__ C, int M, int N, int K)
{
  __shared__ float As[16][68];
  __shared__ float Bs[16][68];
  const int tid = threadIdx.x;
  const int m0 = blockIdx.y * 64, n0 = blockIdx.x * 64;
  const int ty = tid >> 4, tx = tid & 15;
  const int arow = tid >> 2, akq = (tid & 3) * 4;
  const int brow = tid >> 4, bcq = (tid & 15) * 4;
  const int zc = gridDim.z;
  const int kc = K / zc;
  const int kbase = blockIdx.z * kc;
  float* __restrict__ Co = C + (size_t)blockIdx.z * M * N;
  float acc[4][4] = {};
  for (int k0 = kbase; k0 < kbase + kc; k0 += 16) {
    float4 a4 = *(const float4*)(A + (size_t)(m0 + arow) * K + k0 + akq);
    float4 b4 = *(const float4*)(B + (size_t)(k0 + brow) * N + n0 + bcq);
    As[akq+0][arow] = a4.x; As[akq+1][arow] = a4.y; As[akq+2][arow] = a4.z; As[akq+3][arow] = a4.w;
    *(float4*)&Bs[brow][bcq] = b4;
    __syncthreads();
#pragma unroll
    for (int k = 0; k < 16; ++k) {
      float4 a = *(const float4*)&As[k][ty*4];
      float4 b = *(const float4*)&Bs[k][tx*4];
      float ar[4] = {a.x,a.y,a.z,a.w}, br[4] = {b.x,b.y,b.z,b.w};
#pragma unroll
      for (int i = 0; i < 4; ++i)
#pragma unroll
        for (int j = 0; j < 4; ++j) acc[i][j] = fmaf(ar[i], br[j], acc[i][j]);
    }
    __syncthreads();
  }
#pragma unroll
  for (int i = 0; i < 4; ++i) {
    const int m = m0 + ty*4 + i;
    float4 c; c.x = acc[i][0]; c.y = acc[i][1]; c.z = acc[i][2]; c.w = acc[i][3];
    *(float4*)(Co + (size_t)m * N + n0 + tx*4) = c;
  }
}

// ---------------- fp32 GEMM TN: Cslab[z][M,N] = A[Kc,M]^T * B[Kc,N] -----------
// Precision-critical (gWp = dp^T @ v). Deterministic slab split-K.
__global__ __launch_bounds__(256) void gemm_tn_kernel(
    const float* __restrict__ A, const float* __restrict__ B,
    float* __restrict__ C, int M, int N, int K)
{
  __shared__ float As[16][68];
  __shared__ float Bs[16][68];
  const int tid = threadIdx.x;
  const int m0 = blockIdx.y * 64, n0 = blockIdx.x * 64;
  const int ty = tid >> 4, tx = tid & 15;
  const int row = tid >> 4, cq = (tid & 15) * 4;
  const int kc = K / gridDim.z;
  const int kbase = blockIdx.z * kc;
  float* __restrict__ Co = C + (size_t)blockIdx.z * M * N;
  float acc[4][4] = {};
  for (int k0 = kbase; k0 < kbase + kc; k0 += 16) {
    float4 a4 = *(const float4*)(A + (size_t)(k0 + row) * M + m0 + cq);
    float4 b4 = *(const float4*)(B + (size_t)(k0 + row) * N + n0 + cq);
    *(float4*)&As[row][cq] = a4;
    *(float4*)&Bs[row][cq] = b4;
    __syncthreads();
#pragma unroll
    for (int k = 0; k < 16; ++k) {
      float4 a = *(const float4*)&As[k][ty*4];
      float4 b = *(const float4*)&Bs[k][tx*4];
      float ar[4] = {a.x,a.y,a.z,a.w}, br[4] = {b.x,b.y,b.z,b.w};
#pragma unroll
      for (int i = 0; i < 4; ++i)
#pragma unroll
        for (int j = 0; j < 4; ++j) acc[i][j] = fmaf(ar[i], br[j], acc[i][j]);
    }
    __syncthreads();
  }
#pragma unroll
  for (int i = 0; i < 4; ++i) {
    const int m = m0 + ty*4 + i;
    float4 c; c.x = acc[i][0]; c.y = acc[i][1]; c.z = acc[i][2]; c.w = acc[i][3];
    *(float4*)(Co + (size_t)m * N + n0 + tx*4) = c;
  }
}

// ---------------- LayerNorm forward (wave per token) --------------------------
// nslab>1 (slow path): input p is a slab base (nslab partials of [T,F] at
// stride TF); x = sum slabs + pbias, written to x_out (fp32 p) before LN.
__global__ __launch_bounds__(256) void ln_fwd_kernel(
    const float* __restrict__ p, const float* __restrict__ v,
    const float* __restrict__ tmat, const float* __restrict__ stepb,
    const float* __restrict__ sdot, const float* __restrict__ gamma,
    const float* __restrict__ beta, float* __restrict__ o,
    unsigned short* __restrict__ obf,
    float* __restrict__ mu_out, float* __restrict__ rstd_out, int fastmode,
    int nslab, const float* __restrict__ pbias, float* __restrict__ x_out)
{
  const int t = blockIdx.x * 4 + (threadIdx.x >> 6);
  const int lane = threadIdx.x & 63;
  const int f0 = lane * 4, f1 = 256 + lane * 4;
  const size_t TFs = (size_t)T_TOK * F_DIM;
  const float* pr = p + (size_t)t * F_DIM;
  float4 x0 = *(const float4*)(pr + f0);
  float4 x1 = *(const float4*)(pr + f1);
  if (nslab > 1) {
    for (int k = 1; k < nslab; ++k) {
      float4 a = *(const float4*)(pr + (size_t)k * TFs + f0);
      float4 b = *(const float4*)(pr + (size_t)k * TFs + f1);
      x0.x += a.x; x0.y += a.y; x0.z += a.z; x0.w += a.w;
      x1.x += b.x; x1.y += b.y; x1.z += b.z; x1.w += b.w;
    }
    if (pbias) {
      float4 a = *(const float4*)(pbias + f0);
      float4 b = *(const float4*)(pbias + f1);
      x0.x += a.x; x0.y += a.y; x0.z += a.z; x0.w += a.w;
      x1.x += b.x; x1.y += b.y; x1.z += b.z; x1.w += b.w;
    }
    if (x_out) {
      *(float4*)(x_out + (size_t)t * F_DIM + f0) = x0;
      *(float4*)(x_out + (size_t)t * F_DIM + f1) = x1;
    }
  }
  if (fastmode) {
    const float* vr = v + (size_t)t * F_DIM;
    const float* tr = tmat + (size_t)t * F_DIM;
    const float sdt = sdot[t];
    float4 v0 = *(const float4*)(vr + f0), v1 = *(const float4*)(vr + f1);
    float4 t0 = *(const float4*)(tr + f0), t1 = *(const float4*)(tr + f1);
    float4 s0 = *(const float4*)(stepb + f0), s1 = *(const float4*)(stepb + f1);
    x0.x -= v0.x * (t0.x + s0.x * sdt);
    x0.y -= v0.y * (t0.y + s0.y * sdt);
    x0.z -= v0.z * (t0.z + s0.z * sdt);
    x0.w -= v0.w * (t0.w + s0.w * sdt);
    x1.x -= v1.x * (t1.x + s1.x * sdt);
    x1.y -= v1.y * (t1.y + s1.y * sdt);
    x1.z -= v1.z * (t1.z + s1.z * sdt);
    x1.w -= v1.w * (t1.w + s1.w * sdt);
  }
  float s  = x0.x + x0.y + x0.z + x0.w + x1.x + x1.y + x1.z + x1.w;
  float ss = x0.x*x0.x + x0.y*x0.y + x0.z*x0.z + x0.w*x0.w
           + x1.x*x1.x + x1.y*x1.y + x1.z*x1.z + x1.w*x1.w;
  s = wave_sum(s); ss = wave_sum(ss);
  const float mu = s * (1.f / F_DIM);
  const float var = ss * (1.f / F_DIM) - mu * mu;
  const float rstd = rsqrtf(var + LN_EPS);
  float4 g0 = *(const float4*)(gamma + f0), g1 = *(const float4*)(gamma + f1);
  float4 b0 = *(const float4*)(beta + f0),  b1 = *(const float4*)(beta + f1);
  float4 y0, y1;
  y0.x = (x0.x - mu) * rstd * g0.x + b0.x;
  y0.y = (x0.y - mu) * rstd * g0.y + b0.y;
  y0.z = (x0.z - mu) * rstd * g0.z + b0.z;
  y0.w = (x0.w - mu) * rstd * g0.w + b0.w;
  y1.x = (x1.x - mu) * rstd * g1.x + b1.x;
  y1.y = (x1.y - mu) * rstd * g1.y + b1.y;
  y1.z = (x1.z - mu) * rstd * g1.z + b1.z;
  y1.w = (x1.w - mu) * rstd * g1.w + b1.w;
  if (o) {
    *(float4*)(o + (size_t)t * F_DIM + f0) = y0;
    *(float4*)(o + (size_t)t * F_DIM + f1) = y1;
  }
  ushort4 u0, u1;
  u0.x = f2bf(y0.x); u0.y = f2bf(y0.y); u0.z = f2bf(y0.z); u0.w = f2bf(y0.w);
  u1.x = f2bf(y1.x); u1.y = f2bf(y1.y); u1.z = f2bf(y1.z); u1.w = f2bf(y1.w);
  *(ushort4*)(obf + (size_t)t * F_DIM + f0) = u0;
  *(ushort4*)(obf + (size_t)t * F_DIM + f1) = u1;
  if (!fastmode && lane == 0) { mu_out[t] = mu; rstd_out[t] = rstd; }
}

// ---------------- LayerNorm backward (wave per token) -------------------------
__global__ __launch_bounds__(256) void ln_bwd_kernel(
    const float* __restrict__ U, const float* __restrict__ z_,
    const float* __restrict__ E,
    const int* __restrict__ labels, const float* __restrict__ gamma,
    const float* __restrict__ p, const float* __restrict__ mu_,
    const float* __restrict__ rstd_, float* __restrict__ dp,
    unsigned short* __restrict__ dpbf)
{
  const int t = blockIdx.x * 4 + (threadIdx.x >> 6);
  const int lane = threadIdx.x & 63;
  const int f0 = lane * 4, f1 = 256 + lane * 4;
  const int lab = labels[t];
  const float mu = mu_[t], rstd = rstd_[t];
  const float zr = 1.f / z_[t];
  const float* dor = U + (size_t)t * F_DIM;
  const float* er  = E + (size_t)lab * F_DIM;
  const float* pr  = p + (size_t)t * F_DIM;
  alignas(16) float d[8], e[8], g[8], x[8];
  *(float4*)&d[0] = *(const float4*)(dor + f0); *(float4*)&d[4] = *(const float4*)(dor + f1);
  *(float4*)&e[0] = *(const float4*)(er + f0);  *(float4*)&e[4] = *(const float4*)(er + f1);
  *(float4*)&g[0] = *(const float4*)(gamma + f0); *(float4*)&g[4] = *(const float4*)(gamma + f1);
  *(float4*)&x[0] = *(const float4*)(pr + f0);  *(float4*)&x[4] = *(const float4*)(pr + f1);
  float dh[8], xh[8];
  float s1 = 0.f, s2 = 0.f;
#pragma unroll
  for (int i = 0; i < 8; ++i) {
    dh[i] = (d[i] * zr - e[i]) * g[i];
    xh[i] = (x[i] - mu) * rstd;
    s1 += dh[i];
    s2 += dh[i] * xh[i];
  }
  s1 = wave_sum(s1); s2 = wave_sum(s2);
  const float c1 = s1 * (1.f / F_DIM), c2 = s2 * (1.f / F_DIM);
  alignas(16) float outv[8];
#pragma unroll
  for (int i = 0; i < 8; ++i) outv[i] = rstd * (dh[i] - c1 - xh[i] * c2);
  *(float4*)(dp + (size_t)t * F_DIM + f0) = *(float4*)&outv[0];
  *(float4*)(dp + (size_t)t * F_DIM + f1) = *(float4*)&outv[4];
  ushort4 u0, u1;
  u0.x = f2bf(outv[0]); u0.y = f2bf(outv[1]); u0.z = f2bf(outv[2]); u0.w = f2bf(outv[3]);
  u1.x = f2bf(outv[4]); u1.y = f2bf(outv[5]); u1.z = f2bf(outv[6]); u1.w = f2bf(outv[7]);
  *(ushort4*)(dpbf + (size_t)t * F_DIM + f0) = u0;
  *(ushort4*)(dpbf + (size_t)t * F_DIM + f1) = u1;
}

// ---------------- column sum with atomics -------------------------------------
__global__ __launch_bounds__(256) void colsum_kernel(
    const float* __restrict__ X, float* __restrict__ out)
{
  const int f = blockIdx.x * 256 + threadIdx.x;
  const int t0 = blockIdx.y * 128;
  float s = 0.f;
  for (int r = 0; r < 128; ++r) s += X[(size_t)(t0 + r) * F_DIM + f];
  atomicAdd(out + f, s);
}

// ---------------- sdot[t] = dot(v[t,:], gbp) ----------------------------------
__global__ __launch_bounds__(256) void sdot_kernel(
    const float* __restrict__ v, const float* __restrict__ gbp,
    float* __restrict__ sd)
{
  const int t = blockIdx.x * 4 + (threadIdx.x >> 6);
  const int lane = threadIdx.x & 63;
  const int f0 = lane * 4, f1 = 256 + lane * 4;
  const float* vr = v + (size_t)t * F_DIM;
  float4 a0 = *(const float4*)(vr + f0), a1 = *(const float4*)(vr + f1);
  float4 b0 = *(const float4*)(gbp + f0), b1 = *(const float4*)(gbp + f1);
  float s = a0.x*b0.x + a0.y*b0.y + a0.z*b0.z + a0.w*b0.w
          + a1.x*b1.x + a1.y*b1.y + a1.z*b1.z + a1.w*b1.w;
  s = wave_sum(s);
  if (lane == 0) sd[t] = s;
}

// ---------------- expS = exp(o·E^T + ob - SHIFT); z[t] += rowsum --------------
// XCD-chunk swizzle: physical flat id pf -> (low = pf%8, r = pf/8),
// s = low*chunk + r; j = s&15 (t-tile), g = s>>4 (v-tile). Blocks on one XCD
// residue cover a CONTIGUOUS run of v-tiles -> each Ebf v-tile lives on ~1 XCD.
__global__ __launch_bounds__(256, 2) void expsum_kernel(
    const unsigned short* __restrict__ obf, const unsigned short* __restrict__ Ebf,
    const float* __restrict__ ob, unsigned short* __restrict__ expS,
    float* __restrict__ z, int vbase)
{
  __shared__ __align__(16) unsigned short Es[128 * 64];
  __shared__ __align__(16) unsigned short Os[128 * 64];
  const int tid = threadIdx.x;
  const int w = tid >> 6, lane = tid & 63;
  const int c15 = lane & 15, q = lane >> 4;
  const int pf    = (int)blockIdx.x + (int)gridDim.x * (int)blockIdx.y;
  const int chunk = ((int)gridDim.x * (int)gridDim.y) >> 3;   // blocks per XCD
  const int s_    = (pf & 7) * chunk + (pf >> 3);
  const int t0 = (s_ & 15) * 128;
  const int v0 = vbase + (s_ >> 4) * 128;
  const int vw = v0 + (w & 1) * 64, tw = t0 + (w >> 1) * 64;
  f32x4 acc[4][4];
#pragma unroll
  for (int mi = 0; mi < 4; ++mi)
#pragma unroll
    for (int nj = 0; nj < 4; ++nj) acc[mi][nj] = (f32x4){0.f, 0.f, 0.f, 0.f};
  for (int it = 0; it < F_DIM / 64; ++it) {
    const int kb = it * 64;
#pragma unroll
    for (int i = 0; i < 4; ++i) {
      const int gid = (w * 4 + i) * 64 + lane;
      const int row = gid >> 3, col3 = gid & 7;
      const int colsrc = col3 ^ (row & 7);
      gld16(Ebf + (size_t)(v0 + row) * F_DIM + kb + colsrc * 8, &Es[(w * 4 + i) * 512]);
      gld16(obf + (size_t)(t0 + row) * F_DIM + kb + colsrc * 8, &Os[(w * 4 + i) * 512]);
    }
    __syncthreads();
#pragma unroll
    for (int kk = 0; kk < 2; ++kk) {
      const int g = (kk * 4 + q) ^ (c15 & 7);
      bf16x8 af[4], bfr[4];
#pragma unroll
      for (int mi = 0; mi < 4; ++mi) {
        const int row = (w & 1) * 64 + mi * 16 + c15;
        af[mi] = *(const bf16x8*)&Es[(row * 8 + g) * 8];
      }
#pragma unroll
      for (int nj = 0; nj < 4; ++nj) {
        const int row = (w >> 1) * 64 + nj * 16 + c15;
        bfr[nj] = *(const bf16x8*)&Os[(row * 8 + g) * 8];
      }
#pragma unroll
      for (int mi = 0; mi < 4; ++mi)
#pragma unroll
        for (int nj = 0; nj < 4; ++nj)
          acc[mi][nj] = __builtin_amdgcn_mfma_f32_16x16x32_bf16(af[mi], bfr[nj], acc[mi][nj], 0, 0, 0);
    }
    __syncthreads();
  }
  float obv[4][4];
#pragma unroll
  for (int mi = 0; mi < 4; ++mi)
    *(float4*)obv[mi] = *(const float4*)&ob[vw + mi * 16 + q * 4];
#pragma unroll
  for (int nj = 0; nj < 4; ++nj) {
    const int t = tw + nj * 16 + c15;
    float zsum = 0.f;
#pragma unroll
    for (int mi = 0; mi < 4; ++mi) {
      float e0 = __expf(acc[mi][nj][0] + obv[mi][0] - SHIFT);
      float e1 = __expf(acc[mi][nj][1] + obv[mi][1] - SHIFT);
      float e2 = __expf(acc[mi][nj][2] + obv[mi][2] - SHIFT);
      float e3 = __expf(acc[mi][nj][3] + obv[mi][3] - SHIFT);
      zsum += e0 + e1 + e2 + e3;
      if (expS) {
        const int vloc = vw - vbase + mi * 16 + q * 4;
        ushort4 u; u.x = f2bf(e0); u.y = f2bf(e1); u.z = f2bf(e2); u.w = f2bf(e3);
        *(ushort4*)&expS[(size_t)t * VHALF + vloc] = u;
      }
    }
    zsum += __shfl_xor(zsum, 16);
    zsum += __shfl_xor(zsum, 32);
    if (q == 0) atomicAdd(&z[t], zsum);
  }
}

// ---------------- U += expS(half) @ E(half) (NT bf16 GEMM, split-K atomics) ---
// XCD-group swizzle: the 4 f-tile blocks sharing one P-tile are mapped to the
// same (flat % 8) residue so they co-reside on one XCD's L2.
// Grid (4, 16, NKC=25) = 1600 blocks (6.25 blocks/CU: makespan + overlap).
__global__ __launch_bounds__(256, 2) void gemm_pe_kernel(
    const unsigned short* __restrict__ P, const unsigned short* __restrict__ Etbf,
    float* __restrict__ dO, int vbase)
{
  __shared__ __align__(16) unsigned short As[128 * 64];
  __shared__ __align__(16) unsigned short Bs[128 * 64];
  const int tid = threadIdx.x;
  const int w = tid >> 6, lane = tid & 63;
  const int c15 = lane & 15, q = lane >> 4;
  // physical flat id (x fastest)
  const int pf   = (int)blockIdx.x + 4 * (int)blockIdx.y + 64 * (int)blockIdx.z;
  const int low  = pf & 7;          // XCD residue (round-robin heuristic)
  const int rest = pf >> 3;         // 0..199
  const int j    = rest & 3;        // member: f-tile
  const int ghi  = rest >> 2;       // 0..49
  const int g    = ghi * 8 + low;   // group 0..399 = (t-tile, k-chunk), bijective
  const int n0 = j * 128;
  const int m0 = (g & 15) * 128;
  const int klbase = (g >> 4) * KC;
  const int mw = (w & 1) * 64, nw = (w >> 1) * 64;
  f32x4 acc[4][4];
#pragma unroll
  for (int mi = 0; mi < 4; ++mi)
#pragma unroll
    for (int nj = 0; nj < 4; ++nj) acc[mi][nj] = (f32x4){0.f, 0.f, 0.f, 0.f};
  for (int it = 0; it < KC / 64; ++it) {
    const int kl = klbase + it * 64;
#pragma unroll
    for (int i = 0; i < 4; ++i) {
      const int gid = (w * 4 + i) * 64 + lane;
      const int row = gid >> 3, col = gid & 7;
      const int colsrc = col ^ (row & 7);
      gld16(P + (size_t)(m0 + row) * VHALF + kl + colsrc * 8, &As[(w * 4 + i) * 512]);
      gld16(Etbf + (size_t)(n0 + row) * V_DIM + vbase + kl + colsrc * 8, &Bs[(w * 4 + i) * 512]);
    }
    __syncthreads();
#pragma unroll
    for (int kk = 0; kk < 2; ++kk) {
      const int gg = (kk * 4 + q) ^ (c15 & 7);
      bf16x8 af[4], bfr[4];
#pragma unroll
      for (int mi = 0; mi < 4; ++mi) {
        const int row = mw + mi * 16 + c15;
        af[mi] = *(const bf16x8*)&As[(row * 8 + gg) * 8];
      }
#pragma unroll
      for (int nj = 0; nj < 4; ++nj) {
        const int row = nw + nj * 16 + c15;
        bfr[nj] = *(const bf16x8*)&Bs[(row * 8 + gg) * 8];
      }
#pragma unroll
      for (int mi = 0; mi < 4; ++mi)
#pragma unroll
        for (int nj = 0; nj < 4; ++nj)
          acc[mi][nj] = __builtin_amdgcn_mfma_f32_16x16x32_bf16(af[mi], bfr[nj], acc[mi][nj], 0, 0, 0);
    }
    __syncthreads();
  }
#pragma unroll
  for (int mi = 0; mi < 4; ++mi)
#pragma unroll
    for (int nj = 0; nj < 4; ++nj) {
      const int f = n0 + nw + nj * 16 + c15;
#pragma unroll
      for (int r = 0; r < 4; ++r) {
        const int t = m0 + mw + mi * 16 + q * 4 + r;
        atomicAdd(&dO[(size_t)t * F_DIM + f], acc[mi][nj][r]);
      }
    }
}

// ---------------- fast loss: SHIFT + log z - (logit at label) -----------------
__global__ __launch_bounds__(256) void fast_loss_kernel(
    const float* __restrict__ of, const float* __restrict__ E,
    const float* __restrict__ ob, const int* __restrict__ labels,
    const float* __restrict__ zf,
    float* __restrict__ out)
{
  const int t = blockIdx.x * 4 + (threadIdx.x >> 6);
  const int lane = threadIdx.x & 63;
  const int f0 = lane * 4, f1 = 256 + lane * 4;
  const int lab = labels[t];
  const float* orow = of + (size_t)t * F_DIM;
  const float* er = E + (size_t)lab * F_DIM;
  float4 a0 = *(const float4*)(orow + f0), a1 = *(const float4*)(orow + f1);
  float4 b0 = *(const float4*)(er + f0),   b1 = *(const float4*)(er + f1);
  float s = a0.x*b0.x + a0.y*b0.y + a0.z*b0.z + a0.w*b0.w
          + a1.x*b1.x + a1.y*b1.y + a1.z*b1.z + a1.w*b1.w;
  s = wave_sum(s);
  if (lane == 0) out[t] = SHIFT + logf(zf[t]) - (s + ob[lab]);
}

// ==============================================================================
extern "C" void kernel_launch(void* const* d_in, const int* in_sizes, int n_in,
                              void* d_out, int out_size, void* d_ws, size_t ws_size,
                              hipStream_t stream)
{
  const float* h      = (const float*)d_in[0];
  const float* E      = (const float*)d_in[1];
  const float* ob     = (const float*)d_in[2];
  const int*   labels = (const int*)d_in[3];
  const float* Wh     = (const float*)d_in[4];
  const float* bh     = (const float*)d_in[5];
  const float* hb     = (const float*)d_in[6];
  const float* Wp     = (const float*)d_in[7];
  const float* bp     = (const float*)d_in[8];
  const float* gamma  = (const float*)d_in[9];
  const float* beta   = (const float*)d_in[10];
  const float* stepW  = (const float*)d_in[11];
  const float* stepb  = (const float*)d_in[12];

  float* out_loss = (float*)d_out;                 // [2048]
  float* out_gWh  = out_loss + T_TOK;              // [512,1024]
  float* out_ghb  = out_gWh + F_DIM * H_DIM;       // [512]
  float* out_gWp  = out_ghb + F_DIM;               // [512,512]
  float* out_gbp  = out_gWp + F_DIM * F_DIM;       // [512]

  float* ws = (float*)d_ws;
  const size_t TF = (size_t)T_TOK * F_DIM;
  float* v_   = ws;
  float* p_   = ws + TF;
  float* dO_  = ws + 2 * TF;   // U = expS @ E (pre 1/z scale); also slab region
  float* dp_  = ws + 3 * TF;
  float* dv_  = ws + 4 * TF;
  float* u_   = ws + 5 * TF;   // (slab use only; u values live in of_)
  float* tm_  = ws + 6 * TF;
  float* of_  = ws + 7 * TF;
  float* sm   = ws + 8 * TF;
  float* mu_    = sm;
  float* rstd_  = sm + 2048;
  float* zs_    = sm + 4096;
  float* zf_    = sm + 6144;
  float* sd_    = sm + 8192;
  unsigned short* obf   = (unsigned short*)(sm + 10240);
  unsigned short* ofbf  = obf + TF;
  unsigned short* dpbf  = ofbf + TF;
  unsigned short* dvTbf = dpbf + TF;
  unsigned short* hbfT  = dvTbf + TF;                      // [1024,2048]
  unsigned short* WpTbf = hbfT + (size_t)T_TOK * H_DIM;    // [512,512]
  unsigned short* Ebf   = WpTbf + (size_t)F_DIM * F_DIM;
  unsigned short* Etbf  = Ebf + (size_t)V_DIM * F_DIM;
  unsigned short* Pbuf  = Etbf + (size_t)V_DIM * F_DIM;    // expS [2048, VHALF]

  (void)u_;

  // zero small atomic accumulators in one launch (dO_ zero after slow ln_fwd)
  zero_multi_kernel<<<8, 256, 0, stream>>>(zs_, T_TOK, zf_, T_TOK,
                                           out_ghb, F_DIM, out_gbp, F_DIM);

  // conversions
  convertE_kernel<<<dim3(V_DIM / 64, F_DIM / 64), 256, 0, stream>>>(E, Ebf, Etbf);
  convT_kernel<<<dim3(T_TOK / 64, H_DIM / 64), 256, 0, stream>>>(h, hbfT, T_TOK, H_DIM);
  convT_kernel<<<dim3(F_DIM / 64, F_DIM / 64), 256, 0, stream>>>(Wp, WpTbf, F_DIM, F_DIM);

  // v = relu(h @ Wh^T + bh + hb): slab split-K=4 into dO_..u_ then fused reduce
  gemm_nt_kernel<<<dim3(F_DIM / 64, T_TOK / 64, 4), 256, 0, stream>>>(
      h, nullptr, Wh, dO_, T_TOK, F_DIM, H_DIM, nullptr, nullptr, 0);
  reduceK_kernel<<<(int)(TF / 4 / 256), 256, 0, stream>>>(
      (const float4*)dO_, (float4*)v_, (int)(TF / 4), 4, bh, hb, 1, nullptr);
  // p = v @ Wp^T + bp: slab split-K=4 into dO_..u_; reduce fused into ln_fwd
  gemm_nt_kernel<<<dim3(8, 32, 4), 256, 0, stream>>>(
      v_, nullptr, Wp, dO_, T_TOK, F_DIM, F_DIM, nullptr, nullptr, 0);
  // o = LN(sum slabs + bp); also writes p_ (fp32) for ln_bwd / fast path
  ln_fwd_kernel<<<512, 256, 0, stream>>>(
      dO_, nullptr, nullptr, nullptr, nullptr, gamma, beta, nullptr, obf,
      mu_, rstd_, 0, 4, bp, p_);
  // now dO_ becomes the U accumulator
  zero4_kernel<<<(int)(TF / 4 / 256), 256, 0, stream>>>((float4*)dO_, (int)(TF / 4));
  // vocab halves: expS + z, then U accumulation (split-K=25, KC=640, XCD-grouped)
  expsum_kernel<<<dim3(T_TOK / 128, VHALF / 128), 256, 0, stream>>>(
      obf, Ebf, ob, Pbuf, zs_, 0);
  gemm_pe_kernel<<<dim3(F_DIM / 128, T_TOK / 128, NKC), 256, 0, stream>>>(Pbuf, Etbf, dO_, 0);
  expsum_kernel<<<dim3(T_TOK / 128, VHALF / 128), 256, 0, stream>>>(
      obf, Ebf, ob, Pbuf, zs_, VHALF);
  gemm_pe_kernel<<<dim3(F_DIM / 128, T_TOK / 128, NKC), 256, 0, stream>>>(Pbuf, Etbf, dO_, VHALF);
  // dp = LN backward(U/z - E[label])  -> dp fp32 + dpbf
  ln_bwd_kernel<<<512, 256, 0, stream>>>(dO_, zs_, E, labels, gamma, p_, mu_, rstd_, dp_, dpbf);
  // gbp = colsum(dp)  (fp32)
  colsum_kernel<<<dim3(2, 16), 256, 0, stream>>>(dp_, out_gbp);
  // gWp = dp^T @ v: slab split-K=8 into dv_+u_ (8 x 1MB), reduce
  gemm_tn_kernel<<<dim3(8, 8, 8), 256, 0, stream>>>(dp_, v_, dv_, F_DIM, F_DIM, T_TOK);
  reduceK_kernel<<<F_DIM * F_DIM / 4 / 256, 256, 0, stream>>>(
      (const float4*)dv_, (float4*)out_gWp, F_DIM * F_DIM / 4, 8, nullptr, nullptr, 0, nullptr);
  // sdot = v . gbp  (fp32)
  sdot_kernel<<<512, 256, 0, stream>>>(v_, out_gbp, sd_);
  // u = v @ gWp: slab split-K=4 into dO_..u_ (dp_ fp32 dead from here), reduce -> of_
  gemm_nn_kernel<<<dim3(8, 32, 4), 256, 0, stream>>>(v_, out_gWp, dO_, T_TOK, F_DIM, F_DIM);
  reduceK_kernel<<<(int)(TF / 4 / 256), 256, 0, stream>>>(
      (const float4*)dO_, (float4*)of_, (int)(TF / 4), 4, nullptr, nullptr, 0, nullptr);
  // tmat = (v*u) @ stepW^T: slab split-K=4 into dO_..u_, reduce -> tm_
  gemm_nt_kernel<<<dim3(8, 32, 4), 256, 0, stream>>>(
      v_, of_, stepW, dO_, T_TOK, F_DIM, F_DIM, nullptr, nullptr, 0);
  reduceK_kernel<<<(int)(TF / 4 / 256), 256, 0, stream>>>(
      (const float4*)dO_, (float4*)tm_, (int)(TF / 4), 4, nullptr, nullptr, 0, nullptr);
  // dv = (dp @ Wp) * (v > 0): bf16 slab split-K=4 into dO_..u_, masked reduce -> dv_
  gemm_bf_nt_kernel<<<dim3(4, 16, 4), 256, 0, stream>>>(
      dpbf, WpTbf, T_TOK, F_DIM, F_DIM, nullptr, dO_, 0);
  reduceK_kernel<<<(int)(TF / 4 / 256), 256, 0, stream>>>(
      (const float4*)dO_, (float4*)dv_, (int)(TF / 4), 4, nullptr, nullptr, 0, v_);
  // ghb = colsum(dv)
  colsum_kernel<<<dim3(2, 16), 256, 0, stream>>>(dv_, out_ghb);
  convT_kernel<<<dim3(T_TOK / 64, F_DIM / 64), 256, 0, stream>>>(dv_, dvTbf, T_TOK, F_DIM);
  // gWh = dv^T @ h: bf16 slab split-K=8 (8 x 2MB into dO_+dp_), reduce -> out_gWh
  gemm_bf_nt_kernel<<<dim3(8, 4, 8), 256, 0, stream>>>(
      dvTbf, hbfT, F_DIM, H_DIM, T_TOK, nullptr, dO_, 0);
  reduceK_kernel<<<F_DIM * H_DIM / 4 / 256, 256, 0, stream>>>(
      (const float4*)dO_, (float4*)out_gWh, F_DIM * H_DIM / 4, 8, nullptr, nullptr, 0, nullptr);
  // o_fast = LN(p - v*(tmat + stepb*sdot))  (overwrites of_ after its last use)
  ln_fwd_kernel<<<512, 256, 0, stream>>>(
      p_, v_, tm_, stepb, sd_, gamma, beta, of_, ofbf, nullptr, nullptr, 1,
      1, nullptr, nullptr);
  // fast path: z only (full vocab in one launch)
  expsum_kernel<<<dim3(T_TOK / 128, V_DIM / 128), 256, 0, stream>>>(
      ofbf, Ebf, ob, nullptr, zf_, 0);
  // fast_loss
  fast_loss_kernel<<<512, 256, 0, stream>>>(of_, E, ob, labels, zf_, out_loss);
}

// Round 9
// 617.048 us; speedup vs baseline: 1.1644x; 1.1644x over previous
//
#include <hip/hip_runtime.h>
#include <cstddef>
#include <math.h>

#define T_TOK 2048
#define F_DIM 512
#define H_DIM 1024
#define V_DIM 32000
#define VHALF 16000
#define NKC   10
#define KC    1600
#define LN_EPS 1e-5f
#define SHIFT 20.0f

typedef __attribute__((ext_vector_type(8))) short bf16x8;
typedef __attribute__((ext_vector_type(4))) float f32x4;

__device__ __forceinline__ unsigned short f2bf(float x) {
  unsigned int u = __float_as_uint(x);
  u += 0x7fffu + ((u >> 16) & 1u);
  return (unsigned short)(u >> 16);
}

// async global->LDS, 16B per lane; LDS dest = wave-uniform base + lane*16
__device__ __forceinline__ void gld16(const unsigned short* gsrc, unsigned short* ldst) {
  __builtin_amdgcn_global_load_lds(
      (const __attribute__((address_space(1))) unsigned int*)gsrc,
      (__attribute__((address_space(3))) unsigned int*)ldst, 16, 0, 0);
}

__device__ inline float wave_sum(float x) {
#pragma unroll
  for (int off = 32; off > 0; off >>= 1) x += __shfl_xor(x, off, 64);
  return x;
}

// ---------------- zero ----------------
__global__ void zero_kernel(float* __restrict__ p, int n) {
  int i = blockIdx.x * 256 + threadIdx.x;
  if (i < n) p[i] = 0.f;
}

__global__ void zero4_kernel(float4* __restrict__ p, int n4) {
  int i = blockIdx.x * 256 + threadIdx.x;
  if (i < n4) {
    float4 z; z.x = 0.f; z.y = 0.f; z.z = 0.f; z.w = 0.f;
    p[i] = z;
  }
}

// fused zeroing of up to 4 small arrays (one launch instead of four)
__global__ void zero_multi_kernel(float* __restrict__ a, int na,
                                  float* __restrict__ b, int nb,
                                  float* __restrict__ c, int nc,
                                  float* __restrict__ d, int nd) {
  int i = blockIdx.x * 256 + threadIdx.x;
  if (i < na) a[i] = 0.f;
  if (i < nb) b[i] = 0.f;
  if (i < nc) c[i] = 0.f;
  if (i < nd) d[i] = 0.f;
}

// -- sum nslab slabs of n4 float4s; opt. bias (row width F_DIM), relu, mask ---
// mask semantics match gemm_bf_nt epilogue: component zeroed where !(mask>0).
__global__ __launch_bounds__(256) void reduceK_kernel(
    const float4* __restrict__ parts, float4* __restrict__ out, int n4, int nslab,
    const float* __restrict__ bias1, const float* __restrict__ bias2, int relu,
    const float* __restrict__ maskv) {
  const int i = blockIdx.x * 256 + threadIdx.x;
  if (i >= n4) return;
  float4 s = parts[i];
  for (int k = 1; k < nslab; ++k) {
    float4 p = parts[(size_t)k * n4 + i];
    s.x += p.x; s.y += p.y; s.z += p.z; s.w += p.w;
  }
  const int c = (i & (F_DIM / 4 - 1)) * 4;
  if (bias1) {
    float4 b = *(const float4*)(bias1 + c);
    s.x += b.x; s.y += b.y; s.z += b.z; s.w += b.w;
  }
  if (bias2) {
    float4 b = *(const float4*)(bias2 + c);
    s.x += b.x; s.y += b.y; s.z += b.z; s.w += b.w;
  }
  if (relu) {
    s.x = fmaxf(s.x, 0.f); s.y = fmaxf(s.y, 0.f);
    s.z = fmaxf(s.z, 0.f); s.w = fmaxf(s.w, 0.f);
  }
  if (maskv) {
    float4 m = ((const float4*)maskv)[i];
    if (!(m.x > 0.f)) s.x = 0.f;
    if (!(m.y > 0.f)) s.y = 0.f;
    if (!(m.z > 0.f)) s.z = 0.f;
    if (!(m.w > 0.f)) s.w = 0.f;
  }
  out[i] = s;
}

// ---------------- fp32 [R,C] -> bf16 [C,R] (transpose) ------------------------
__global__ __launch_bounds__(256) void convT_kernel(
    const float* __restrict__ in, unsigned short* __restrict__ out, int R, int C) {
  __shared__ unsigned short tile[64][65];
  const int r0 = blockIdx.x * 64, c0 = blockIdx.y * 64;
  const int rr = threadIdx.x >> 4, cc4 = (threadIdx.x & 15) * 4;
#pragma unroll
  for (int ps = 0; ps < 4; ++ps) {
    const int row = ps * 16 + rr;
    float4 x = *(const float4*)&in[(size_t)(r0 + row) * C + c0 + cc4];
    tile[row][cc4 + 0] = f2bf(x.x); tile[row][cc4 + 1] = f2bf(x.y);
    tile[row][cc4 + 2] = f2bf(x.z); tile[row][cc4 + 3] = f2bf(x.w);
  }
  __syncthreads();
#pragma unroll
  for (int ps = 0; ps < 4; ++ps) {
    const int orow = ps * 16 + rr;
    ushort4 u;
    u.x = tile[cc4 + 0][orow]; u.y = tile[cc4 + 1][orow];
    u.z = tile[cc4 + 2][orow]; u.w = tile[cc4 + 3][orow];
    *(ushort4*)&out[(size_t)(c0 + orow) * R + r0 + cc4] = u;
  }
}

// ---------------- convert E to bf16 (row-major) + bf16 transposed ------------
__global__ __launch_bounds__(256) void convertE_kernel(
    const float* __restrict__ E, unsigned short* __restrict__ Ebf,
    unsigned short* __restrict__ Etbf)
{
  __shared__ float tile[64][65];
  const int tid = threadIdx.x;
  const int v0 = blockIdx.x * 64, f0 = blockIdx.y * 64;
  const int r = tid >> 4, cq = (tid & 15) * 4;
#pragma unroll
  for (int ps = 0; ps < 4; ++ps) {
    const int row = ps * 16 + r;
    float4 x = *(const float4*)&E[(size_t)(v0 + row) * F_DIM + f0 + cq];
    tile[row][cq + 0] = x.x; tile[row][cq + 1] = x.y;
    tile[row][cq + 2] = x.z; tile[row][cq + 3] = x.w;
    ushort4 u; u.x = f2bf(x.x); u.y = f2bf(x.y); u.z = f2bf(x.z); u.w = f2bf(x.w);
    *(ushort4*)&Ebf[(size_t)(v0 + row) * F_DIM + f0 + cq] = u;
  }
  __syncthreads();
#pragma unroll
  for (int ps = 0; ps < 4; ++ps) {
    const int frow = ps * 16 + r;
    ushort4 u;
    u.x = f2bf(tile[cq + 0][frow]); u.y = f2bf(tile[cq + 1][frow]);
    u.z = f2bf(tile[cq + 2][frow]); u.w = f2bf(tile[cq + 3][frow]);
    *(ushort4*)&Etbf[(size_t)(f0 + frow) * V_DIM + v0 + cq] = u;
  }
}

// ---------------- generic bf16 NT GEMM: C[M,N] = A[M,K] * B[N,K]^T ------------
// Used only OUTSIDE the c_t precision chain (dv, gWh).
// gridDim.z>1: atomic_f=1 -> atomicAdd; atomic_f=0 -> slab mode (plain stores
// at outf + z*M*N; reduceK sums slabs).
__global__ __launch_bounds__(256, 2) void gemm_bf_nt_kernel(
    const unsigned short* __restrict__ A, const unsigned short* __restrict__ B,
    int M, int N, int K,
    const float* __restrict__ maskv,
    float* __restrict__ outf, int atomic_f)
{
  __shared__ __align__(16) unsigned short As[128 * 64];
  __shared__ __align__(16) unsigned short Bs[128 * 64];
  const int tid = threadIdx.x;
  const int w = tid >> 6, lane = tid & 63;
  const int c15 = lane & 15, q = lane >> 4;
  const int n0 = blockIdx.x * 128, m0 = blockIdx.y * 128;
  const int kc = K / gridDim.z;
  const int kbase = blockIdx.z * kc;
  const int mw = (w & 1) * 64, nw = (w >> 1) * 64;
  float* __restrict__ outp = outf;
  if (!atomic_f && gridDim.z > 1) outp = outf + (size_t)blockIdx.z * M * N;
  f32x4 acc[4][4];
#pragma unroll
  for (int mi = 0; mi < 4; ++mi)
#pragma unroll
    for (int nj = 0; nj < 4; ++nj) acc[mi][nj] = (f32x4){0.f, 0.f, 0.f, 0.f};
  for (int it = 0; it < kc / 64; ++it) {
    const int kb = kbase + it * 64;
#pragma unroll
    for (int i = 0; i < 4; ++i) {
      const int gid = (w * 4 + i) * 64 + lane;
      const int row = gid >> 3, col = gid & 7;
      const int colsrc = col ^ (row & 7);
      gld16(A + (size_t)(m0 + row) * K + kb + colsrc * 8, &As[(w * 4 + i) * 512]);
      gld16(B + (size_t)(n0 + row) * K + kb + colsrc * 8, &Bs[(w * 4 + i) * 512]);
    }
    __syncthreads();
#pragma unroll
    for (int kk = 0; kk < 2; ++kk) {
      const int g = (kk * 4 + q) ^ (c15 & 7);
      bf16x8 af[4], bfr[4];
#pragma unroll
      for (int mi = 0; mi < 4; ++mi) {
        const int row = mw + mi * 16 + c15;
        af[mi] = *(const bf16x8*)&As[(row * 8 + g) * 8];
      }
#pragma unroll
      for (int nj = 0; nj < 4; ++nj) {
        const int row = nw + nj * 16 + c15;
        bfr[nj] = *(const bf16x8*)&Bs[(row * 8 + g) * 8];
      }
#pragma unroll
      for (int mi = 0; mi < 4; ++mi)
#pragma unroll
        for (int nj = 0; nj < 4; ++nj)
          acc[mi][nj] = __builtin_amdgcn_mfma_f32_16x16x32_bf16(af[mi], bfr[nj], acc[mi][nj], 0, 0, 0);
    }
    __syncthreads();
  }
#pragma unroll
  for (int mi = 0; mi < 4; ++mi)
#pragma unroll
    for (int nj = 0; nj < 4; ++nj) {
      const int n = n0 + nw + nj * 16 + c15;
#pragma unroll
      for (int r = 0; r < 4; ++r) {
        const int m = m0 + mw + mi * 16 + q * 4 + r;
        const size_t idx = (size_t)m * N + n;
        float v = acc[mi][nj][r];
        if (maskv && !(maskv[idx] > 0.f)) v = 0.f;
        if (atomic_f) atomicAdd(outf + idx, v); else outp[idx] = v;
      }
    }
}

// ---------------- fp32 GEMM NT: C[M,N] = (A ⊙ A2)[M,K] * B[N,K]^T -------------
// Precision-critical chain (v, p, tmat). gridDim.z>1: deterministic slab
// split-K — each z writes a full partial at C + z*M*N (plain stores);
// reduceK_kernel (or fused consumer) sums slabs and applies bias/relu.
__global__ __launch_bounds__(256) void gemm_nt_kernel(
    const float* __restrict__ A, const float* __restrict__ A2,
    const float* __restrict__ B, float* __restrict__ C,
    int M, int N, int K,
    const float* __restrict__ bias1, const float* __restrict__ bias2, int relu)
{
  __shared__ float As[16][68];
  __shared__ float Bs[16][68];
  const int tid = threadIdx.x;
  const int m0 = blockIdx.y * 64, n0 = blockIdx.x * 64;
  const int ty = tid >> 4, tx = tid & 15;
  const int lrow = tid >> 2, lkq = (tid & 3) * 4;
  const int zc = gridDim.z;
  const int kc = K / zc;
  const int kbase = blockIdx.z * kc;
  float* __restrict__ Co = C + (size_t)blockIdx.z * M * N;
  float acc[4][4] = {};
  for (int k0 = kbase; k0 < kbase + kc; k0 += 16) {
    float4 a4 = *(const float4*)(A + (size_t)(m0 + lrow) * K + k0 + lkq);
    if (A2) {
      float4 u4 = *(const float4*)(A2 + (size_t)(m0 + lrow) * K + k0 + lkq);
      a4.x *= u4.x; a4.y *= u4.y; a4.z *= u4.z; a4.w *= u4.w;
    }
    float4 b4 = *(const float4*)(B + (size_t)(n0 + lrow) * K + k0 + lkq);
    As[lkq+0][lrow] = a4.x; As[lkq+1][lrow] = a4.y; As[lkq+2][lrow] = a4.z; As[lkq+3][lrow] = a4.w;
    Bs[lkq+0][lrow] = b4.x; Bs[lkq+1][lrow] = b4.y; Bs[lkq+2][lrow] = b4.z; Bs[lkq+3][lrow] = b4.w;
    __syncthreads();
#pragma unroll
    for (int k = 0; k < 16; ++k) {
      float4 a = *(const float4*)&As[k][ty*4];
      float4 b = *(const float4*)&Bs[k][tx*4];
      float ar[4] = {a.x,a.y,a.z,a.w}, br[4] = {b.x,b.y,b.z,b.w};
#pragma unroll
      for (int i = 0; i < 4; ++i)
#pragma unroll
        for (int j = 0; j < 4; ++j) acc[i][j] = fmaf(ar[i], br[j], acc[i][j]);
    }
    __syncthreads();
  }
  if (zc == 1) {
#pragma unroll
    for (int i = 0; i < 4; ++i) {
      const int m = m0 + ty*4 + i;
      float cr[4];
#pragma unroll
      for (int j = 0; j < 4; ++j) {
        const int n = n0 + tx*4 + j;
        float v = acc[i][j];
        if (bias1) v += bias1[n];
        if (bias2) v += bias2[n];
        if (relu) v = fmaxf(v, 0.f);
        cr[j] = v;
      }
      float4 c; c.x = cr[0]; c.y = cr[1]; c.z = cr[2]; c.w = cr[3];
      *(float4*)(C + (size_t)m * N + n0 + tx*4) = c;
    }
  } else {
#pragma unroll
    for (int i = 0; i < 4; ++i) {
      const int m = m0 + ty*4 + i;
      float4 c; c.x = acc[i][0]; c.y = acc[i][1]; c.z = acc[i][2]; c.w = acc[i][3];
      *(float4*)(Co + (size_t)m * N + n0 + tx*4) = c;
    }
  }
}

// ---------------- fp32 GEMM NN: C[M,N] = A[M,K] * B[K,N] ----------------------
// Precision-critical (u = v @ gWp). gridDim.z>1: slab split-K (see gemm_nt).
__global__ __launch_bounds__(256) void gemm_nn_kernel(
    const float* __restrict__ A, const float* __restrict__ B,
    float* __restrict__ C, int M, int N, int K)
{
  __shared__ float As[16][68];
  __shared__ float Bs[16][68];
  const int tid = threadIdx.x;
  const int m0 = blockIdx.y * 64, n0 = blockIdx.x * 64;
  const int ty = tid >> 4, tx = tid & 15;
  const int arow = tid >> 2, akq = (tid & 3) * 4;
  const int brow = tid >> 4, bcq = (tid & 15) * 4;
  const int zc = gridDim.z;
  const int kc = K / zc;
  const int kbase = blockIdx.z * kc;
  float* __restrict__ Co = C + (size_t)blockIdx.z * M * N;
  float acc[4][4] = {};
  for (int k0 = kbase; k0 < kbase + kc; k0 += 16) {
    float4 a4 = *(const float4*)(A + (size_t)(m0 + arow) * K + k0 + akq);
    float4 b4 = *(const float4*)(B + (size_t)(k0 + brow) * N + n0 + bcq);
    As[akq+0][arow] = a4.x; As[akq+1][arow] = a4.y; As[akq+2][arow] = a4.z; As[akq+3][arow] = a4.w;
    *(float4*)&Bs[brow][bcq] = b4;
    __syncthreads();
#pragma unroll
    for (int k = 0; k < 16; ++k) {
      float4 a = *(const float4*)&As[k][ty*4];
      float4 b = *(const float4*)&Bs[k][tx*4];
      float ar[4] = {a.x,a.y,a.z,a.w}, br[4] = {b.x,b.y,b.z,b.w};
#pragma unroll
      for (int i = 0; i < 4; ++i)
#pragma unroll
        for (int j = 0; j < 4; ++j) acc[i][j] = fmaf(ar[i], br[j], acc[i][j]);
    }
    __syncthreads();
  }
#pragma unroll
  for (int i = 0; i < 4; ++i) {
    const int m = m0 + ty*4 + i;
    float4 c; c.x = acc[i][0]; c.y = acc[i][1]; c.z = acc[i][2]; c.w = acc[i][3];
    *(float4*)(Co + (size_t)m * N + n0 + tx*4) = c;
  }
}

// ---------------- fp32 GEMM TN: Cslab[z][M,N] = A[Kc,M]^T * B[Kc,N] -----------
// Precision-critical (gWp = dp^T @ v). Deterministic slab split-K.
__global__ __launch_bounds__(256) void gemm_tn_kernel(
    const float* __restrict__ A, const float* __restrict__ B,
    float* __restrict__ C, int M, int N, int K)
{
  __shared__ float As[16][68];
  __shared__ float Bs[16][68];
  const int tid = threadIdx.x;
  const int m0 = blockIdx.y * 64, n0 = blockIdx.x * 64;
  const int ty = tid >> 4, tx = tid & 15;
  const int row = tid >> 4, cq = (tid & 15) * 4;
  const int kc = K / gridDim.z;
  const int kbase = blockIdx.z * kc;
  float* __restrict__ Co = C + (size_t)blockIdx.z * M * N;
  float acc[4][4] = {};
  for (int k0 = kbase; k0 < kbase + kc; k0 += 16) {
    float4 a4 = *(const float4*)(A + (size_t)(k0 + row) * M + m0 + cq);
    float4 b4 = *(const float4*)(B + (size_t)(k0 + row) * N + n0 + cq);
    *(float4*)&As[row][cq] = a4;
    *(float4*)&Bs[row][cq] = b4;
    __syncthreads();
#pragma unroll
    for (int k = 0; k < 16; ++k) {
      float4 a = *(const float4*)&As[k][ty*4];
      float4 b = *(const float4*)&Bs[k][tx*4];
      float ar[4] = {a.x,a.y,a.z,a.w}, br[4] = {b.x,b.y,b.z,b.w};
#pragma unroll
      for (int i = 0; i < 4; ++i)
#pragma unroll
        for (int j = 0; j < 4; ++j) acc[i][j] = fmaf(ar[i], br[j], acc[i][j]);
    }
    __syncthreads();
  }
#pragma unroll
  for (int i = 0; i < 4; ++i) {
    const int m = m0 + ty*4 + i;
    float4 c; c.x = acc[i][0]; c.y = acc[i][1]; c.z = acc[i][2]; c.w = acc[i][3];
    *(float4*)(Co + (size_t)m * N + n0 + tx*4) = c;
  }
}

// ---------------- LayerNorm forward (wave per token) --------------------------
// nslab>1 (slow path): input p is a slab base (nslab partials of [T,F] at
// stride TF); x = sum slabs + pbias, written to x_out (fp32 p) before LN.
__global__ __launch_bounds__(256) void ln_fwd_kernel(
    const float* __restrict__ p, const float* __restrict__ v,
    const float* __restrict__ tmat, const float* __restrict__ stepb,
    const float* __restrict__ sdot, const float* __restrict__ gamma,
    const float* __restrict__ beta, float* __restrict__ o,
    unsigned short* __restrict__ obf,
    float* __restrict__ mu_out, float* __restrict__ rstd_out, int fastmode,
    int nslab, const float* __restrict__ pbias, float* __restrict__ x_out)
{
  const int t = blockIdx.x * 4 + (threadIdx.x >> 6);
  const int lane = threadIdx.x & 63;
  const int f0 = lane * 4, f1 = 256 + lane * 4;
  const size_t TFs = (size_t)T_TOK * F_DIM;
  const float* pr = p + (size_t)t * F_DIM;
  float4 x0 = *(const float4*)(pr + f0);
  float4 x1 = *(const float4*)(pr + f1);
  if (nslab > 1) {
    for (int k = 1; k < nslab; ++k) {
      float4 a = *(const float4*)(pr + (size_t)k * TFs + f0);
      float4 b = *(const float4*)(pr + (size_t)k * TFs + f1);
      x0.x += a.x; x0.y += a.y; x0.z += a.z; x0.w += a.w;
      x1.x += b.x; x1.y += b.y; x1.z += b.z; x1.w += b.w;
    }
    if (pbias) {
      float4 a = *(const float4*)(pbias + f0);
      float4 b = *(const float4*)(pbias + f1);
      x0.x += a.x; x0.y += a.y; x0.z += a.z; x0.w += a.w;
      x1.x += b.x; x1.y += b.y; x1.z += b.z; x1.w += b.w;
    }
    if (x_out) {
      *(float4*)(x_out + (size_t)t * F_DIM + f0) = x0;
      *(float4*)(x_out + (size_t)t * F_DIM + f1) = x1;
    }
  }
  if (fastmode) {
    const float* vr = v + (size_t)t * F_DIM;
    const float* tr = tmat + (size_t)t * F_DIM;
    const float sdt = sdot[t];
    float4 v0 = *(const float4*)(vr + f0), v1 = *(const float4*)(vr + f1);
    float4 t0 = *(const float4*)(tr + f0), t1 = *(const float4*)(tr + f1);
    float4 s0 = *(const float4*)(stepb + f0), s1 = *(const float4*)(stepb + f1);
    x0.x -= v0.x * (t0.x + s0.x * sdt);
    x0.y -= v0.y * (t0.y + s0.y * sdt);
    x0.z -= v0.z * (t0.z + s0.z * sdt);
    x0.w -= v0.w * (t0.w + s0.w * sdt);
    x1.x -= v1.x * (t1.x + s1.x * sdt);
    x1.y -= v1.y * (t1.y + s1.y * sdt);
    x1.z -= v1.z * (t1.z + s1.z * sdt);
    x1.w -= v1.w * (t1.w + s1.w * sdt);
  }
  float s  = x0.x + x0.y + x0.z + x0.w + x1.x + x1.y + x1.z + x1.w;
  float ss = x0.x*x0.x + x0.y*x0.y + x0.z*x0.z + x0.w*x0.w
           + x1.x*x1.x + x1.y*x1.y + x1.z*x1.z + x1.w*x1.w;
  s = wave_sum(s); ss = wave_sum(ss);
  const float mu = s * (1.f / F_DIM);
  const float var = ss * (1.f / F_DIM) - mu * mu;
  const float rstd = rsqrtf(var + LN_EPS);
  float4 g0 = *(const float4*)(gamma + f0), g1 = *(const float4*)(gamma + f1);
  float4 b0 = *(const float4*)(beta + f0),  b1 = *(const float4*)(beta + f1);
  float4 y0, y1;
  y0.x = (x0.x - mu) * rstd * g0.x + b0.x;
  y0.y = (x0.y - mu) * rstd * g0.y + b0.y;
  y0.z = (x0.z - mu) * rstd * g0.z + b0.z;
  y0.w = (x0.w - mu) * rstd * g0.w + b0.w;
  y1.x = (x1.x - mu) * rstd * g1.x + b1.x;
  y1.y = (x1.y - mu) * rstd * g1.y + b1.y;
  y1.z = (x1.z - mu) * rstd * g1.z + b1.z;
  y1.w = (x1.w - mu) * rstd * g1.w + b1.w;
  if (o) {
    *(float4*)(o + (size_t)t * F_DIM + f0) = y0;
    *(float4*)(o + (size_t)t * F_DIM + f1) = y1;
  }
  ushort4 u0, u1;
  u0.x = f2bf(y0.x); u0.y = f2bf(y0.y); u0.z = f2bf(y0.z); u0.w = f2bf(y0.w);
  u1.x = f2bf(y1.x); u1.y = f2bf(y1.y); u1.z = f2bf(y1.z); u1.w = f2bf(y1.w);
  *(ushort4*)(obf + (size_t)t * F_DIM + f0) = u0;
  *(ushort4*)(obf + (size_t)t * F_DIM + f1) = u1;
  if (!fastmode && lane == 0) { mu_out[t] = mu; rstd_out[t] = rstd; }
}

// ---------------- LayerNorm backward (wave per token) -------------------------
__global__ __launch_bounds__(256) void ln_bwd_kernel(
    const float* __restrict__ U, const float* __restrict__ z_,
    const float* __restrict__ E,
    const int* __restrict__ labels, const float* __restrict__ gamma,
    const float* __restrict__ p, const float* __restrict__ mu_,
    const float* __restrict__ rstd_, float* __restrict__ dp,
    unsigned short* __restrict__ dpbf)
{
  const int t = blockIdx.x * 4 + (threadIdx.x >> 6);
  const int lane = threadIdx.x & 63;
  const int f0 = lane * 4, f1 = 256 + lane * 4;
  const int lab = labels[t];
  const float mu = mu_[t], rstd = rstd_[t];
  const float zr = 1.f / z_[t];
  const float* dor = U + (size_t)t * F_DIM;
  const float* er  = E + (size_t)lab * F_DIM;
  const float* pr  = p + (size_t)t * F_DIM;
  alignas(16) float d[8], e[8], g[8], x[8];
  *(float4*)&d[0] = *(const float4*)(dor + f0); *(float4*)&d[4] = *(const float4*)(dor + f1);
  *(float4*)&e[0] = *(const float4*)(er + f0);  *(float4*)&e[4] = *(const float4*)(er + f1);
  *(float4*)&g[0] = *(const float4*)(gamma + f0); *(float4*)&g[4] = *(const float4*)(gamma + f1);
  *(float4*)&x[0] = *(const float4*)(pr + f0);  *(float4*)&x[4] = *(const float4*)(pr + f1);
  float dh[8], xh[8];
  float s1 = 0.f, s2 = 0.f;
#pragma unroll
  for (int i = 0; i < 8; ++i) {
    dh[i] = (d[i] * zr - e[i]) * g[i];
    xh[i] = (x[i] - mu) * rstd;
    s1 += dh[i];
    s2 += dh[i] * xh[i];
  }
  s1 = wave_sum(s1); s2 = wave_sum(s2);
  const float c1 = s1 * (1.f / F_DIM), c2 = s2 * (1.f / F_DIM);
  alignas(16) float outv[8];
#pragma unroll
  for (int i = 0; i < 8; ++i) outv[i] = rstd * (dh[i] - c1 - xh[i] * c2);
  *(float4*)(dp + (size_t)t * F_DIM + f0) = *(float4*)&outv[0];
  *(float4*)(dp + (size_t)t * F_DIM + f1) = *(float4*)&outv[4];
  ushort4 u0, u1;
  u0.x = f2bf(outv[0]); u0.y = f2bf(outv[1]); u0.z = f2bf(outv[2]); u0.w = f2bf(outv[3]);
  u1.x = f2bf(outv[4]); u1.y = f2bf(outv[5]); u1.z = f2bf(outv[6]); u1.w = f2bf(outv[7]);
  *(ushort4*)(dpbf + (size_t)t * F_DIM + f0) = u0;
  *(ushort4*)(dpbf + (size_t)t * F_DIM + f1) = u1;
}

// ---------------- column sum with atomics -------------------------------------
__global__ __launch_bounds__(256) void colsum_kernel(
    const float* __restrict__ X, float* __restrict__ out)
{
  const int f = blockIdx.x * 256 + threadIdx.x;
  const int t0 = blockIdx.y * 128;
  float s = 0.f;
  for (int r = 0; r < 128; ++r) s += X[(size_t)(t0 + r) * F_DIM + f];
  atomicAdd(out + f, s);
}

// ---------------- sdot[t] = dot(v[t,:], gbp) ----------------------------------
__global__ __launch_bounds__(256) void sdot_kernel(
    const float* __restrict__ v, const float* __restrict__ gbp,
    float* __restrict__ sd)
{
  const int t = blockIdx.x * 4 + (threadIdx.x >> 6);
  const int lane = threadIdx.x & 63;
  const int f0 = lane * 4, f1 = 256 + lane * 4;
  const float* vr = v + (size_t)t * F_DIM;
  float4 a0 = *(const float4*)(vr + f0), a1 = *(const float4*)(vr + f1);
  float4 b0 = *(const float4*)(gbp + f0), b1 = *(const float4*)(gbp + f1);
  float s = a0.x*b0.x + a0.y*b0.y + a0.z*b0.z + a0.w*b0.w
          + a1.x*b1.x + a1.y*b1.y + a1.z*b1.z + a1.w*b1.w;
  s = wave_sum(s);
  if (lane == 0) sd[t] = s;
}

// ---------------- expS = exp(o·E^T + ob - SHIFT); z[t] += rowsum --------------
// XCD-chunk swizzle: physical flat id pf -> (low = pf%8, r = pf/8),
// s = low*chunk + r; j = s&15 (t-tile), g = s>>4 (v-tile). Blocks on one XCD
// residue cover a CONTIGUOUS run of v-tiles -> each Ebf v-tile lives on ~1 XCD.
__global__ __launch_bounds__(256, 2) void expsum_kernel(
    const unsigned short* __restrict__ obf, const unsigned short* __restrict__ Ebf,
    const float* __restrict__ ob, unsigned short* __restrict__ expS,
    float* __restrict__ z, int vbase)
{
  __shared__ __align__(16) unsigned short Es[128 * 64];
  __shared__ __align__(16) unsigned short Os[128 * 64];
  const int tid = threadIdx.x;
  const int w = tid >> 6, lane = tid & 63;
  const int c15 = lane & 15, q = lane >> 4;
  const int pf    = (int)blockIdx.x + (int)gridDim.x * (int)blockIdx.y;
  const int chunk = ((int)gridDim.x * (int)gridDim.y) >> 3;   // blocks per XCD
  const int s_    = (pf & 7) * chunk + (pf >> 3);
  const int t0 = (s_ & 15) * 128;
  const int v0 = vbase + (s_ >> 4) * 128;
  const int vw = v0 + (w & 1) * 64, tw = t0 + (w >> 1) * 64;
  f32x4 acc[4][4];
#pragma unroll
  for (int mi = 0; mi < 4; ++mi)
#pragma unroll
    for (int nj = 0; nj < 4; ++nj) acc[mi][nj] = (f32x4){0.f, 0.f, 0.f, 0.f};
  for (int it = 0; it < F_DIM / 64; ++it) {
    const int kb = it * 64;
#pragma unroll
    for (int i = 0; i < 4; ++i) {
      const int gid = (w * 4 + i) * 64 + lane;
      const int row = gid >> 3, col3 = gid & 7;
      const int colsrc = col3 ^ (row & 7);
      gld16(Ebf + (size_t)(v0 + row) * F_DIM + kb + colsrc * 8, &Es[(w * 4 + i) * 512]);
      gld16(obf + (size_t)(t0 + row) * F_DIM + kb + colsrc * 8, &Os[(w * 4 + i) * 512]);
    }
    __syncthreads();
#pragma unroll
    for (int kk = 0; kk < 2; ++kk) {
      const int g = (kk * 4 + q) ^ (c15 & 7);
      bf16x8 af[4], bfr[4];
#pragma unroll
      for (int mi = 0; mi < 4; ++mi) {
        const int row = (w & 1) * 64 + mi * 16 + c15;
        af[mi] = *(const bf16x8*)&Es[(row * 8 + g) * 8];
      }
#pragma unroll
      for (int nj = 0; nj < 4; ++nj) {
        const int row = (w >> 1) * 64 + nj * 16 + c15;
        bfr[nj] = *(const bf16x8*)&Os[(row * 8 + g) * 8];
      }
#pragma unroll
      for (int mi = 0; mi < 4; ++mi)
#pragma unroll
        for (int nj = 0; nj < 4; ++nj)
          acc[mi][nj] = __builtin_amdgcn_mfma_f32_16x16x32_bf16(af[mi], bfr[nj], acc[mi][nj], 0, 0, 0);
    }
    __syncthreads();
  }
  float obv[4][4];
#pragma unroll
  for (int mi = 0; mi < 4; ++mi)
    *(float4*)obv[mi] = *(const float4*)&ob[vw + mi * 16 + q * 4];
#pragma unroll
  for (int nj = 0; nj < 4; ++nj) {
    const int t = tw + nj * 16 + c15;
    float zsum = 0.f;
#pragma unroll
    for (int mi = 0; mi < 4; ++mi) {
      float e0 = __expf(acc[mi][nj][0] + obv[mi][0] - SHIFT);
      float e1 = __expf(acc[mi][nj][1] + obv[mi][1] - SHIFT);
      float e2 = __expf(acc[mi][nj][2] + obv[mi][2] - SHIFT);
      float e3 = __expf(acc[mi][nj][3] + obv[mi][3] - SHIFT);
      zsum += e0 + e1 + e2 + e3;
      if (expS) {
        const int vloc = vw - vbase + mi * 16 + q * 4;
        ushort4 u; u.x = f2bf(e0); u.y = f2bf(e1); u.z = f2bf(e2); u.w = f2bf(e3);
        *(ushort4*)&expS[(size_t)t * VHALF + vloc] = u;
      }
    }
    zsum += __shfl_xor(zsum, 16);
    zsum += __shfl_xor(zsum, 32);
    if (q == 0) atomicAdd(&z[t], zsum);
  }
}

// ---------------- U += expS(half) @ E(half) (NT bf16 GEMM, split-K atomics) ---
// XCD-group swizzle: the 4 f-tile blocks sharing one P-tile are mapped to the
// same (flat % 8) residue so they co-reside on one XCD's L2.
// Grid (4, 16, NKC=10) = 640 blocks — measured optimum (NKC=5 and 25 both worse).
__global__ __launch_bounds__(256, 2) void gemm_pe_kernel(
    const unsigned short* __restrict__ P, const unsigned short* __restrict__ Etbf,
    float* __restrict__ dO, int vbase)
{
  __shared__ __align__(16) unsigned short As[128 * 64];
  __shared__ __align__(16) unsigned short Bs[128 * 64];
  const int tid = threadIdx.x;
  const int w = tid >> 6, lane = tid & 63;
  const int c15 = lane & 15, q = lane >> 4;
  // physical flat id (x fastest)
  const int pf   = (int)blockIdx.x + 4 * (int)blockIdx.y + 64 * (int)blockIdx.z;
  const int low  = pf & 7;          // XCD residue (round-robin heuristic)
  const int rest = pf >> 3;         // 0..79
  const int j    = rest & 3;        // member: f-tile
  const int ghi  = rest >> 2;       // 0..19
  const int g    = ghi * 8 + low;   // group 0..159 = (t-tile, k-chunk), bijective
  const int n0 = j * 128;
  const int m0 = (g & 15) * 128;
  const int klbase = (g >> 4) * KC;
  const int mw = (w & 1) * 64, nw = (w >> 1) * 64;
  f32x4 acc[4][4];
#pragma unroll
  for (int mi = 0; mi < 4; ++mi)
#pragma unroll
    for (int nj = 0; nj < 4; ++nj) acc[mi][nj] = (f32x4){0.f, 0.f, 0.f, 0.f};
  for (int it = 0; it < KC / 64; ++it) {
    const int kl = klbase + it * 64;
#pragma unroll
    for (int i = 0; i < 4; ++i) {
      const int gid = (w * 4 + i) * 64 + lane;
      const int row = gid >> 3, col = gid & 7;
      const int colsrc = col ^ (row & 7);
      gld16(P + (size_t)(m0 + row) * VHALF + kl + colsrc * 8, &As[(w * 4 + i) * 512]);
      gld16(Etbf + (size_t)(n0 + row) * V_DIM + vbase + kl + colsrc * 8, &Bs[(w * 4 + i) * 512]);
    }
    __syncthreads();
#pragma unroll
    for (int kk = 0; kk < 2; ++kk) {
      const int gg = (kk * 4 + q) ^ (c15 & 7);
      bf16x8 af[4], bfr[4];
#pragma unroll
      for (int mi = 0; mi < 4; ++mi) {
        const int row = mw + mi * 16 + c15;
        af[mi] = *(const bf16x8*)&As[(row * 8 + gg) * 8];
      }
#pragma unroll
      for (int nj = 0; nj < 4; ++nj) {
        const int row = nw + nj * 16 + c15;
        bfr[nj] = *(const bf16x8*)&Bs[(row * 8 + gg) * 8];
      }
#pragma unroll
      for (int mi = 0; mi < 4; ++mi)
#pragma unroll
        for (int nj = 0; nj < 4; ++nj)
          acc[mi][nj] = __builtin_amdgcn_mfma_f32_16x16x32_bf16(af[mi], bfr[nj], acc[mi][nj], 0, 0, 0);
    }
    __syncthreads();
  }
#pragma unroll
  for (int mi = 0; mi < 4; ++mi)
#pragma unroll
    for (int nj = 0; nj < 4; ++nj) {
      const int f = n0 + nw + nj * 16 + c15;
#pragma unroll
      for (int r = 0; r < 4; ++r) {
        const int t = m0 + mw + mi * 16 + q * 4 + r;
        atomicAdd(&dO[(size_t)t * F_DIM + f], acc[mi][nj][r]);
      }
    }
}

// ---------------- fast loss: SHIFT + log z - (logit at label) -----------------
__global__ __launch_bounds__(256) void fast_loss_kernel(
    const float* __restrict__ of, const float* __restrict__ E,
    const float* __restrict__ ob, const int* __restrict__ labels,
    const float* __restrict__ zf,
    float* __restrict__ out)
{
  const int t = blockIdx.x * 4 + (threadIdx.x >> 6);
  const int lane = threadIdx.x & 63;
  const int f0 = lane * 4, f1 = 256 + lane * 4;
  const int lab = labels[t];
  const float* orow = of + (size_t)t * F_DIM;
  const float* er = E + (size_t)lab * F_DIM;
  float4 a0 = *(const float4*)(orow + f0), a1 = *(const float4*)(orow + f1);
  float4 b0 = *(const float4*)(er + f0),   b1 = *(const float4*)(er + f1);
  float s = a0.x*b0.x + a0.y*b0.y + a0.z*b0.z + a0.w*b0.w
          + a1.x*b1.x + a1.y*b1.y + a1.z*b1.z + a1.w*b1.w;
  s = wave_sum(s);
  if (lane == 0) out[t] = SHIFT + logf(zf[t]) - (s + ob[lab]);
}

// ==============================================================================
extern "C" void kernel_launch(void* const* d_in, const int* in_sizes, int n_in,
                              void* d_out, int out_size, void* d_ws, size_t ws_size,
                              hipStream_t stream)
{
  const float* h      = (const float*)d_in[0];
  const float* E      = (const float*)d_in[1];
  const float* ob     = (const float*)d_in[2];
  const int*   labels = (const int*)d_in[3];
  const float* Wh     = (const float*)d_in[4];
  const float* bh     = (const float*)d_in[5];
  const float* hb     = (const float*)d_in[6];
  const float* Wp     = (const float*)d_in[7];
  const float* bp     = (const float*)d_in[8];
  const float* gamma  = (const float*)d_in[9];
  const float* beta   = (const float*)d_in[10];
  const float* stepW  = (const float*)d_in[11];
  const float* stepb  = (const float*)d_in[12];

  float* out_loss = (float*)d_out;                 // [2048]
  float* out_gWh  = out_loss + T_TOK;              // [512,1024]
  float* out_ghb  = out_gWh + F_DIM * H_DIM;       // [512]
  float* out_gWp  = out_ghb + F_DIM;               // [512,512]
  float* out_gbp  = out_gWp + F_DIM * F_DIM;       // [512]

  float* ws = (float*)d_ws;
  const size_t TF = (size_t)T_TOK * F_DIM;
  float* v_   = ws;
  float* p_   = ws + TF;
  float* dO_  = ws + 2 * TF;   // U = expS @ E (pre 1/z scale); also slab region
  float* dp_  = ws + 3 * TF;
  float* dv_  = ws + 4 * TF;
  float* u_   = ws + 5 * TF;   // (slab use only; u values live in of_)
  float* tm_  = ws + 6 * TF;
  float* of_  = ws + 7 * TF;
  float* sm   = ws + 8 * TF;
  float* mu_    = sm;
  float* rstd_  = sm + 2048;
  float* zs_    = sm + 4096;
  float* zf_    = sm + 6144;
  float* sd_    = sm + 8192;
  unsigned short* obf   = (unsigned short*)(sm + 10240);
  unsigned short* ofbf  = obf + TF;
  unsigned short* dpbf  = ofbf + TF;
  unsigned short* dvTbf = dpbf + TF;
  unsigned short* hbfT  = dvTbf + TF;                      // [1024,2048]
  unsigned short* WpTbf = hbfT + (size_t)T_TOK * H_DIM;    // [512,512]
  unsigned short* Ebf   = WpTbf + (size_t)F_DIM * F_DIM;
  unsigned short* Etbf  = Ebf + (size_t)V_DIM * F_DIM;
  unsigned short* Pbuf  = Etbf + (size_t)V_DIM * F_DIM;    // expS [2048, VHALF]

  (void)u_;

  // zero small atomic accumulators in one launch (dO_ zero after slow ln_fwd)
  zero_multi_kernel<<<8, 256, 0, stream>>>(zs_, T_TOK, zf_, T_TOK,
                                           out_ghb, F_DIM, out_gbp, F_DIM);

  // conversions
  convertE_kernel<<<dim3(V_DIM / 64, F_DIM / 64), 256, 0, stream>>>(E, Ebf, Etbf);
  convT_kernel<<<dim3(T_TOK / 64, H_DIM / 64), 256, 0, stream>>>(h, hbfT, T_TOK, H_DIM);
  convT_kernel<<<dim3(F_DIM / 64, F_DIM / 64), 256, 0, stream>>>(Wp, WpTbf, F_DIM, F_DIM);

  // v = relu(h @ Wh^T + bh + hb): slab split-K=4 into dO_..u_ then fused reduce
  gemm_nt_kernel<<<dim3(F_DIM / 64, T_TOK / 64, 4), 256, 0, stream>>>(
      h, nullptr, Wh, dO_, T_TOK, F_DIM, H_DIM, nullptr, nullptr, 0);
  reduceK_kernel<<<(int)(TF / 4 / 256), 256, 0, stream>>>(
      (const float4*)dO_, (float4*)v_, (int)(TF / 4), 4, bh, hb, 1, nullptr);
  // p = v @ Wp^T + bp: slab split-K=4 into dO_..u_; reduce fused into ln_fwd
  gemm_nt_kernel<<<dim3(8, 32, 4), 256, 0, stream>>>(
      v_, nullptr, Wp, dO_, T_TOK, F_DIM, F_DIM, nullptr, nullptr, 0);
  // o = LN(sum slabs + bp); also writes p_ (fp32) for ln_bwd / fast path
  ln_fwd_kernel<<<512, 256, 0, stream>>>(
      dO_, nullptr, nullptr, nullptr, nullptr, gamma, beta, nullptr, obf,
      mu_, rstd_, 0, 4, bp, p_);
  // now dO_ becomes the U accumulator
  zero4_kernel<<<(int)(TF / 4 / 256), 256, 0, stream>>>((float4*)dO_, (int)(TF / 4));
  // vocab halves: expS + z, then U accumulation (split-K=10, KC=1600, XCD-grouped)
  expsum_kernel<<<dim3(T_TOK / 128, VHALF / 128), 256, 0, stream>>>(
      obf, Ebf, ob, Pbuf, zs_, 0);
  gemm_pe_kernel<<<dim3(F_DIM / 128, T_TOK / 128, NKC), 256, 0, stream>>>(Pbuf, Etbf, dO_, 0);
  expsum_kernel<<<dim3(T_TOK / 128, VHALF / 128), 256, 0, stream>>>(
      obf, Ebf, ob, Pbuf, zs_, VHALF);
  gemm_pe_kernel<<<dim3(F_DIM / 128, T_TOK / 128, NKC), 256, 0, stream>>>(Pbuf, Etbf, dO_, VHALF);
  // dp = LN backward(U/z - E[label])  -> dp fp32 + dpbf
  ln_bwd_kernel<<<512, 256, 0, stream>>>(dO_, zs_, E, labels, gamma, p_, mu_, rstd_, dp_, dpbf);
  // gbp = colsum(dp)  (fp32)
  colsum_kernel<<<dim3(2, 16), 256, 0, stream>>>(dp_, out_gbp);
  // gWp = dp^T @ v: slab split-K=8 into dv_+u_ (8 x 1MB), reduce
  gemm_tn_kernel<<<dim3(8, 8, 8), 256, 0, stream>>>(dp_, v_, dv_, F_DIM, F_DIM, T_TOK);
  reduceK_kernel<<<F_DIM * F_DIM / 4 / 256, 256, 0, stream>>>(
      (const float4*)dv_, (float4*)out_gWp, F_DIM * F_DIM / 4, 8, nullptr, nullptr, 0, nullptr);
  // sdot = v . gbp  (fp32)
  sdot_kernel<<<512, 256, 0, stream>>>(v_, out_gbp, sd_);
  // u = v @ gWp: slab split-K=4 into dO_..u_ (dp_ fp32 dead from here), reduce -> of_
  gemm_nn_kernel<<<dim3(8, 32, 4), 256, 0, stream>>>(v_, out_gWp, dO_, T_TOK, F_DIM, F_DIM);
  reduceK_kernel<<<(int)(TF / 4 / 256), 256, 0, stream>>>(
      (const float4*)dO_, (float4*)of_, (int)(TF / 4), 4, nullptr, nullptr, 0, nullptr);
  // tmat = (v*u) @ stepW^T: slab split-K=4 into dO_..u_, reduce -> tm_
  gemm_nt_kernel<<<dim3(8, 32, 4), 256, 0, stream>>>(
      v_, of_, stepW, dO_, T_TOK, F_DIM, F_DIM, nullptr, nullptr, 0);
  reduceK_kernel<<<(int)(TF / 4 / 256), 256, 0, stream>>>(
      (const float4*)dO_, (float4*)tm_, (int)(TF / 4), 4, nullptr, nullptr, 0, nullptr);
  // dv = (dp @ Wp) * (v > 0): bf16 slab split-K=4 into dO_..u_, masked reduce -> dv_
  gemm_bf_nt_kernel<<<dim3(4, 16, 4), 256, 0, stream>>>(
      dpbf, WpTbf, T_TOK, F_DIM, F_DIM, nullptr, dO_, 0);
  reduceK_kernel<<<(int)(TF / 4 / 256), 256, 0, stream>>>(
      (const float4*)dO_, (float4*)dv_, (int)(TF / 4), 4, nullptr, nullptr, 0, v_);
  // ghb = colsum(dv)
  colsum_kernel<<<dim3(2, 16), 256, 0, stream>>>(dv_, out_ghb);
  convT_kernel<<<dim3(T_TOK / 64, F_DIM / 64), 256, 0, stream>>>(dv_, dvTbf, T_TOK, F_DIM);
  // gWh = dv^T @ h: bf16 slab split-K=8 (8 x 2MB into dO_+dp_), reduce -> out_gWh
  gemm_bf_nt_kernel<<<dim3(8, 4, 8), 256, 0, stream>>>(
      dvTbf, hbfT, F_DIM, H_DIM, T_TOK, nullptr, dO_, 0);
  reduceK_kernel<<<F_DIM * H_DIM / 4 / 256, 256, 0, stream>>>(
      (const float4*)dO_, (float4*)out_gWh, F_DIM * H_DIM / 4, 8, nullptr, nullptr, 0, nullptr);
  // o_fast = LN(p - v*(tmat + stepb*sdot))  (overwrites of_ after its last use)
  ln_fwd_kernel<<<512, 256, 0, stream>>>(
      p_, v_, tm_, stepb, sd_, gamma, beta, of_, ofbf, nullptr, nullptr, 1,
      1, nullptr, nullptr);
  // fast path: z only (full vocab in one launch)
  expsum_kernel<<<dim3(T_TOK / 128, V_DIM / 128), 256, 0, stream>>>(
      ofbf, Ebf, ob, nullptr, zf_, 0);
  // fast_loss
  fast_loss_kernel<<<512, 256, 0, stream>>>(of_, E, ob, labels, zf_, out_loss);
}